// Round 5
// baseline (1460.844 us; speedup 1.0000x reference)
//
#include <hip/hip_runtime.h>
#include <hip/hip_fp16.h>

// Problem constants
#define BB  64
#define CIN 256
#define HH  256
#define TT  512
#define G4  1024   // 4*H

typedef _Float16 half2_t __attribute__((ext_vector_type(2)));

__device__ __forceinline__ float fdot2i(int wi, int hi, float acc) {
  half2_t a = __builtin_bit_cast(half2_t, wi);
  half2_t b = __builtin_bit_cast(half2_t, hi);
  return __builtin_amdgcn_fdot2(a, b, acc, false);
}

__device__ __forceinline__ float fast_rcp(float x) { return __builtin_amdgcn_rcpf(x); }
__device__ __forceinline__ float fast_sig(float x) {
  return fast_rcp(1.0f + exp2f(-1.4426950408889634f * x));
}
__device__ __forceinline__ float fast_tanh(float x) {
  return 1.0f - 2.0f * fast_rcp(1.0f + exp2f(2.8853900817779268f * x));
}

// ---------------------------------------------------------------------------
// Kernel 0: W_hh (B,H,4H) fp32 -> Wc (B,4H,H) f16  (per-gate-col contiguous)
// ---------------------------------------------------------------------------
__global__ __launch_bounds__(256) void transpose_whh(const float* __restrict__ W,
                                                     __half* __restrict__ Wc) {
  __shared__ __half tile[32][33];
  int b  = blockIdx.z;
  int j0 = blockIdx.x * 32;
  int k0 = blockIdx.y * 32;
  int tx = threadIdx.x;
  int ty = threadIdx.y;
  const float* Wb = W + (size_t)b * HH * G4;
#pragma unroll
  for (int r = 0; r < 32; r += 8)
    tile[ty + r][tx] = __float2half(Wb[(size_t)(k0 + ty + r) * G4 + j0 + tx]);
  __syncthreads();
  __half* out = Wc + (size_t)b * G4 * HH;
#pragma unroll
  for (int r = 0; r < 32; r += 8)
    out[(size_t)(j0 + ty + r) * HH + k0 + tx] = tile[tx][ty + r];
}

// ---------------------------------------------------------------------------
// Kernel 1: WXT[b][j][t] = sum_i x[b][i][t] * W_ih[b][i][j] + b_h[b][j], f16.
// ---------------------------------------------------------------------------
__global__ __launch_bounds__(256) void gemm_wx(const float* __restrict__ X,
                                               const float* __restrict__ Wih,
                                               const float* __restrict__ bh,
                                               __half* __restrict__ WXT) {
  __shared__ float As[16][64];
  __shared__ float Bs[16][64];
  __shared__ __half tile[64][72];
  int b  = blockIdx.z;
  int t0 = blockIdx.y * 64;
  int j0 = blockIdx.x * 64;
  int tid = threadIdx.x;
  int tx = tid & 15;
  int ty = tid >> 4;
  const float* Xb = X   + (size_t)b * CIN * TT;
  const float* Wb = Wih + (size_t)b * CIN * G4;
  float acc[4][4] = {};
  for (int i0 = 0; i0 < CIN; i0 += 16) {
#pragma unroll
    for (int q = 0; q < 4; ++q) {
      int lin = tid + q * 256;
      int k  = lin >> 6;
      int tt = lin & 63;
      As[k][tt] = Xb[(size_t)(i0 + k) * TT + t0 + tt];
      Bs[k][tt] = Wb[(size_t)(i0 + k) * G4 + j0 + tt];
    }
    __syncthreads();
#pragma unroll
    for (int k = 0; k < 16; ++k) {
      float4 av = *(const float4*)&As[k][ty * 4];
      float4 bv = *(const float4*)&Bs[k][tx * 4];
      float a[4] = {av.x, av.y, av.z, av.w};
      float c[4] = {bv.x, bv.y, bv.z, bv.w};
#pragma unroll
      for (int r = 0; r < 4; ++r)
#pragma unroll
        for (int cc = 0; cc < 4; ++cc)
          acc[r][cc] = fmaf(a[r], c[cc], acc[r][cc]);
    }
    __syncthreads();
  }
  const float* bias = bh + (size_t)b * G4;
#pragma unroll
  for (int cc = 0; cc < 4; ++cc) {
    float bv = bias[j0 + tx * 4 + cc];
    __half2 p0 = __floats2half2_rn(acc[0][cc] + bv, acc[1][cc] + bv);
    __half2 p1 = __floats2half2_rn(acc[2][cc] + bv, acc[3][cc] + bv);
    float2 st;
    st.x = __builtin_bit_cast(float, p0);
    st.y = __builtin_bit_cast(float, p1);
    *(float2*)&tile[tx * 4 + cc][ty * 4] = st;
  }
  __syncthreads();
  int jj = tid >> 2;
  int tg = (tid & 3) * 16;
  __half* dst = WXT + ((size_t)b * G4 + j0 + jj) * TT + t0 + tg;
  *(float4*)dst       = *(const float4*)&tile[jj][tg];
  *(float4*)(dst + 8) = *(const float4*)&tile[jj][tg + 8];
}

// ---------------------------------------------------------------------------
// Kernel 2: recurrence.
//  R5 = R4's hang-proof scaffold + sc0 (same-XCD shared-L2) fast path.
//  R4 counters proved the WORKGROUP fetch_add probe executes MEMORY-SIDE
//  (WRITE_SIZE 600MB ~= 1 HBM write per RMW) -> MALL latency, no gain.
//  - Fast probe : inline-asm `global_load_dwordx2 ... sc0` (L1-bypass, reads
//    the SHARED same-XCD L2 where the peer's sc0 write-through store landed;
//    pair (g,g+64) is same-XCD under m157/m192-validated round-robin).
//  - Fast publish: inline-asm `global_store_dwordx2 ... sc0`.
//  - Safety is STRUCTURAL, not negotiated (no s_getreg/s_memtime/verdicts):
//    6 fast tries/step -> agent-scope load loop (guaranteed progress via the
//    dual agent publish); 4 fallback steps -> fast path off permanently.
//    A stale/false sc0 result can only waste bounded tries, never hang.
//  - Kept from R4: dual-publish, LDS-broadcast dots (uniform ds_read_b128),
//    echo scratch, cross-step prefetch, 1 lgkm-only barrier/step, hreg flush.
// ---------------------------------------------------------------------------
#define LOADWO(m)                                                            \
  int4 w##m = wpo[m];                                                        \
  asm volatile("" : "+v"(w##m.x), "+v"(w##m.y), "+v"(w##m.z), "+v"(w##m.w));
#define LOADWP(m)                                                            \
  int4 w##m = wpp[m - 16];                                                   \
  asm volatile("" : "+v"(w##m.x), "+v"(w##m.y), "+v"(w##m.z), "+v"(w##m.w));

// own-half dots: uniform LDS broadcast of own h pairs
#define DOTO(m)                                                              \
  {                                                                          \
    int4 hx = hpo[m];                                                        \
    a0 = fdot2i(w##m.x, hx.x, a0);                                           \
    a1 = fdot2i(w##m.y, hx.y, a1);                                           \
    a2 = fdot2i(w##m.z, hx.z, a2);                                           \
    a3 = fdot2i(w##m.w, hx.w, a3);                                           \
  }
// peer-half dots: uniform LDS broadcast from wave-private echo scratch
#define DOTP(m)                                                              \
  {                                                                          \
    int4 hx = hpp[m - 16];                                                   \
    a0 = fdot2i(w##m.x, hx.x, a0);                                           \
    a1 = fdot2i(w##m.y, hx.y, a1);                                           \
    a2 = fdot2i(w##m.z, hx.z, a2);                                           \
    a3 = fdot2i(w##m.w, hx.w, a3);                                           \
  }

#define FTAG(vv) ((unsigned)(((vv) >> 32) & 0xFFFull))

// sc0 slot ops. Issue and wait are separate so the load can fly across the
// barrier; "+v"(vv) on the wait makes later uses data-depend on it (rule #18).
#define SLOT_LOAD_SC0(vv, addr)                                              \
  asm volatile("global_load_dwordx2 %0, %1, off sc0" : "=v"(vv) : "v"(addr));
#define SLOT_WAITV(vv)                                                       \
  asm volatile("s_waitcnt vmcnt(0)" : "+v"(vv)::"memory");
#define SLOT_LOADW_SC0(vv, addr)                                             \
  asm volatile("global_load_dwordx2 %0, %1, off sc0\n\ts_waitcnt vmcnt(0)"   \
               : "=v"(vv) : "v"(addr) : "memory");
#define SLOT_STORE_SC0(addr, vv)                                             \
  asm volatile("global_store_dwordx2 %0, %1, off sc0" ::"v"(addr), "v"(vv)   \
               : "memory");

__global__ __attribute__((amdgpu_waves_per_eu(2, 2)))
__launch_bounds__(512) void lstm_rec10(const __half* __restrict__ Wc,
                                       const __half* __restrict__ WXT,
                                       const float* __restrict__ h0,
                                       const float* __restrict__ c0,
                                       float* __restrict__ out,
                                       unsigned long long* __restrict__ fsl,
                                       unsigned long long* __restrict__ ssl) {
  __shared__ __align__(16) unsigned int hshd[2][64];  // own-half h pairs, dbuf
  __shared__ __align__(16) unsigned int scr[8][64];   // per-wave peer echo
  int g    = blockIdx.x;
  int b    = g & 63;
  int half = g >> 6;
  int tid  = threadIdx.x;
  int w    = tid >> 6;
  int lane = tid & 63;
  int i16  = lane & 15;
  int elem = half * 128 + w * 16 + i16;                       // h element
  int j    = (lane >> 4) * 256 + half * 128 + w * 16 + i16;   // gate column
  int kb16 = half * 16;

  // W column, K-halves permuted so blocks 0..15 = own half.
  const int4* wp  = (const int4*)(Wc + ((size_t)b * G4 + j) * HH);
  const int4* wpo = wp + kb16;
  const int4* wpp = wp + (16 - kb16);
  LOADWO(0)  LOADWO(1)  LOADWO(2)  LOADWO(3)  LOADWO(4)  LOADWO(5)  LOADWO(6)  LOADWO(7)
  LOADWO(8)  LOADWO(9)  LOADWO(10) LOADWO(11) LOADWO(12) LOADWO(13) LOADWO(14) LOADWO(15)
  LOADWP(16) LOADWP(17) LOADWP(18) LOADWP(19) LOADWP(20) LOADWP(21) LOADWP(22) LOADWP(23)
  LOADWP(24) LOADWP(25) LOADWP(26) LOADWP(27) LOADWP(28) LOADWP(29) LOADWP(30) LOADWP(31)

  float c_reg = c0[b * HH + elem];

  unsigned long long* fmy = fsl + (size_t)(b * 2 + half) * 2 * 64;
  unsigned long long* fpe = fsl + (size_t)(b * 2 + (half ^ 1)) * 2 * 64;
  unsigned long long* smy = ssl + (size_t)(b * 2 + half) * 2 * 64;
  unsigned long long* spe = ssl + (size_t)(b * 2 + (half ^ 1)) * 2 * 64;

  // Prologue: own-half h0 into LDS + both slot arrays (tag 0, buffer 0).
  if (tid < 64) {
    float f0 = h0[b * HH + half * 128 + 2 * tid];
    float f1 = h0[b * HH + half * 128 + 2 * tid + 1];
    __half2 hp = __floats2half2_rn(f0, f1);
    unsigned int pk = __builtin_bit_cast(unsigned int, hp);
    hshd[0][tid] = pk;
    unsigned long long sv = (unsigned long long)pk;
    unsigned long long* fp0 = &fmy[tid];
    SLOT_STORE_SC0(fp0, sv)
    __hip_atomic_store(&smy[tid], sv, __ATOMIC_RELAXED, __HIP_MEMORY_SCOPE_AGENT);
  }
  __syncthreads();

  const __half* wxTb   = WXT + ((size_t)b * G4 + j) * TT;
  float*        outrow = out + (size_t)b * HH * TT + (size_t)elem * TT;

  int fastp = 1;   // try same-XCD shared-L2 path; demoted on repeated failure
  int fs    = 0;

  // First peer-slot prefetch (t=0, buffer 0).
  unsigned long long v;
  {
    unsigned long long* p0 = &fpe[lane];
    SLOT_LOAD_SC0(v, p0)
  }

  float4 wxcur = *(const float4*)(wxTb);   // steps 0..7
  float  hreg[8];
  for (int t8 = 0; t8 < 64; ++t8) {
    float4 wxnext = *(const float4*)(wxTb + ((size_t)((t8 + 1) & 63) * 8));
#pragma unroll
    for (int u = 0; u < 8; ++u) {
      int t = t8 * 8 + u;

      // Own half: 16 wave-uniform b128 broadcast reads (conflict-free).
      const int4* hpo = (const int4*)&hshd[t & 1][0];
      float a0 = 0.f, a1 = 0.f, a2 = 0.f, a3 = 0.f;
      DOTO(0)  DOTO(1)  DOTO(2)  DOTO(3)  DOTO(4)  DOTO(5)  DOTO(6)  DOTO(7)
      DOTO(8)  DOTO(9)  DOTO(10) DOTO(11) DOTO(12) DOTO(13) DOTO(14) DOTO(15)

      float fw = (u < 2) ? wxcur.x : (u < 4) ? wxcur.y : (u < 6) ? wxcur.z : wxcur.w;
      half2_t hp2 = __builtin_bit_cast(half2_t, fw);
      float wx = (float)((u & 1) ? hp2.y : hp2.x);

      // Poll prefetched slot; bounded fast retries, then guaranteed slow loop.
      if (fastp) { SLOT_WAITV(v) }
      bool bad = (FTAG(v) != (unsigned)t);
      unsigned long long* psf = fpe + ((size_t)(t & 1) * 64 + lane);
      unsigned long long* pss = spe + ((size_t)(t & 1) * 64 + lane);
      int tries = 0, used_slow = 0;
      while (__any(bad)) {
        if (fastp && tries < 6) {
          SLOT_LOADW_SC0(v, psf)
          ++tries;
        } else {
          v = __hip_atomic_load(pss, __ATOMIC_RELAXED, __HIP_MEMORY_SCOPE_AGENT);
          used_slow = 1;
        }
        bad = (FTAG(v) != (unsigned)t);
      }
      if (used_slow) { if (++fs >= 4) fastp = 0; }

      // Echo payload into wave-private scratch, then uniform b128 reads.
      scr[w][lane] = (unsigned)v;
      asm volatile("s_waitcnt lgkmcnt(0)" ::: "memory");
      const int4* hpp = (const int4*)&scr[w][0];
      DOTP(16) DOTP(17) DOTP(18) DOTP(19) DOTP(20) DOTP(21) DOTP(22) DOTP(23)
      DOTP(24) DOTP(25) DOTP(26) DOTP(27) DOTP(28) DOTP(29) DOTP(30) DOTP(31)

      float gate = fast_tanh((a0 + a1) + (a2 + a3) + wx);

      // Intra-wave i/f/g/o gather (all lanes active: shfl needs live sources).
      float ig = __shfl(gate, i16,      64);
      float fg = __shfl(gate, i16 + 16, 64);
      float gg = __shfl(gate, i16 + 32, 64);
      float og = __shfl(gate, i16 + 48, 64);
      c_reg = c_reg * fast_sig(fg) + fast_sig(ig) * fast_tanh(gg);
      float hval = fast_sig(og) * fast_tanh(c_reg);
      hreg[u] = hval;

      __half hh = __float2half(hval);
      unsigned int hb = (unsigned int)__builtin_bit_cast(unsigned short, hh);
      unsigned int nb = (unsigned int)__shfl_xor((int)hb, 1, 64);
      if (lane < 16) {
        ((__half*)&hshd[(t + 1) & 1][0])[w * 16 + i16] = hh;
        if (!(i16 & 1)) {
          unsigned long long sv =
              ((unsigned long long)(unsigned)(t + 1) << 32) |
              (unsigned long long)(hb | (nb << 16));
          size_t so = (size_t)((t + 1) & 1) * 64 + w * 8 + (i16 >> 1);
          unsigned long long* fsp = fmy + so;
          SLOT_STORE_SC0(fsp, sv)
          __hip_atomic_store(smy + so, sv, __ATOMIC_RELAXED, __HIP_MEMORY_SCOPE_AGENT);
        }
      }
      // Prefetch peer slots for t+1 (stays in flight across the barrier).
      {
        size_t no = (size_t)((t + 1) & 1) * 64 + lane;
        if (fastp) {
          unsigned long long* pn = fpe + no;
          SLOT_LOAD_SC0(v, pn)
        } else {
          v = __hip_atomic_load(spe + no, __ATOMIC_RELAXED, __HIP_MEMORY_SCOPE_AGENT);
        }
      }
      // Raw barrier: drain LDS only; slot/output stores + prefetch float across.
      asm volatile("s_waitcnt lgkmcnt(0)" ::: "memory");
      __builtin_amdgcn_s_barrier();
    }
    if (lane < 16) {   // flush 8 steps of h: 32 B contiguous per output row
      float4 lo = make_float4(hreg[0], hreg[1], hreg[2], hreg[3]);
      float4 hi = make_float4(hreg[4], hreg[5], hreg[6], hreg[7]);
      *(float4*)(outrow + t8 * 8)     = lo;
      *(float4*)(outrow + t8 * 8 + 4) = hi;
    }
    wxcur = wxnext;
  }
  if (lane < 16) out[(size_t)BB * HH * TT + (size_t)b * HH + elem] = c_reg;
}

// ---------------------------------------------------------------------------
extern "C" void kernel_launch(void* const* d_in, const int* in_sizes, int n_in,
                              void* d_out, int out_size, void* d_ws, size_t ws_size,
                              hipStream_t stream) {
  const float* x    = (const float*)d_in[0];
  const float* h0   = (const float*)d_in[1];
  const float* c0   = (const float*)d_in[2];
  const float* W_ih = (const float*)d_in[3];
  const float* W_hh = (const float*)d_in[4];
  const float* b_h  = (const float*)d_in[5];
  float* out = (float*)d_out;

  // Workspace layout:
  //   [0,   32 MB)       Wc   : f16 W_hh transposed, (B,4H,H)
  //   [32,  96 MB)       WXT  : f16 wx+bias, (B,4H,T)  -- t contiguous
  //   [96 MB, +128K)     fsl  : fast slots (sc0 / shared-L2 path)
  //   [96 MB+128K,+128K) ssl  : slow slots (agent / MALL path)
  char* ws = (char*)d_ws;
  __half* Wc  = (__half*)ws;
  __half* WXT = (__half*)(ws + (size_t)32 * 1024 * 1024);
  unsigned long long* fsl =
      (unsigned long long*)(ws + (size_t)96 * 1024 * 1024);
  unsigned long long* ssl = fsl + 16384;

  // Tags must never alias a live step value across bench replays: 0xFF.. != any t.
  hipMemsetAsync(fsl, 0xFF, 32768 * sizeof(unsigned long long), stream);
  transpose_whh<<<dim3(G4 / 32, HH / 32, BB), dim3(32, 8), 0, stream>>>(W_hh, Wc);
  gemm_wx<<<dim3(G4 / 64, TT / 64, BB), dim3(256), 0, stream>>>(x, W_ih, b_h, WXT);
  lstm_rec10<<<dim3(128), dim3(512), 0, stream>>>(Wc, WXT, h0, c0, out, fsl, ssl);
}

// Round 6
// 1223.585 us; speedup vs baseline: 1.1939x; 1.1939x over previous
//
#include <hip/hip_runtime.h>
#include <hip/hip_fp16.h>

// Problem constants
#define BB  64
#define CIN 256
#define HH  256
#define TT  512
#define G4  1024   // 4*H

typedef _Float16 half2_t __attribute__((ext_vector_type(2)));

__device__ __forceinline__ float fdot2i(int wi, int hi, float acc) {
  half2_t a = __builtin_bit_cast(half2_t, wi);
  half2_t b = __builtin_bit_cast(half2_t, hi);
  return __builtin_amdgcn_fdot2(a, b, acc, false);
}

__device__ __forceinline__ float fast_rcp(float x) { return __builtin_amdgcn_rcpf(x); }
__device__ __forceinline__ float fast_sig(float x) {
  return fast_rcp(1.0f + exp2f(-1.4426950408889634f * x));
}
__device__ __forceinline__ float fast_tanh(float x) {
  return 1.0f - 2.0f * fast_rcp(1.0f + exp2f(2.8853900817779268f * x));
}

// ---------------------------------------------------------------------------
// Kernel 0: W_hh (B,H,4H) fp32 -> Wc (B,4H,H) f16  (per-gate-col contiguous)
// ---------------------------------------------------------------------------
__global__ __launch_bounds__(256) void transpose_whh(const float* __restrict__ W,
                                                     __half* __restrict__ Wc) {
  __shared__ __half tile[32][33];
  int b  = blockIdx.z;
  int j0 = blockIdx.x * 32;
  int k0 = blockIdx.y * 32;
  int tx = threadIdx.x;
  int ty = threadIdx.y;
  const float* Wb = W + (size_t)b * HH * G4;
#pragma unroll
  for (int r = 0; r < 32; r += 8)
    tile[ty + r][tx] = __float2half(Wb[(size_t)(k0 + ty + r) * G4 + j0 + tx]);
  __syncthreads();
  __half* out = Wc + (size_t)b * G4 * HH;
#pragma unroll
  for (int r = 0; r < 32; r += 8)
    out[(size_t)(j0 + ty + r) * HH + k0 + tx] = tile[tx][ty + r];
}

// ---------------------------------------------------------------------------
// Kernel 1: WXT[b][j][t] = sum_i x[b][i][t] * W_ih[b][i][j] + b_h[b][j], f16.
// ---------------------------------------------------------------------------
__global__ __launch_bounds__(256) void gemm_wx(const float* __restrict__ X,
                                               const float* __restrict__ Wih,
                                               const float* __restrict__ bh,
                                               __half* __restrict__ WXT) {
  __shared__ float As[16][64];
  __shared__ float Bs[16][64];
  __shared__ __half tile[64][72];
  int b  = blockIdx.z;
  int t0 = blockIdx.y * 64;
  int j0 = blockIdx.x * 64;
  int tid = threadIdx.x;
  int tx = tid & 15;
  int ty = tid >> 4;
  const float* Xb = X   + (size_t)b * CIN * TT;
  const float* Wb = Wih + (size_t)b * CIN * G4;
  float acc[4][4] = {};
  for (int i0 = 0; i0 < CIN; i0 += 16) {
#pragma unroll
    for (int q = 0; q < 4; ++q) {
      int lin = tid + q * 256;
      int k  = lin >> 6;
      int tt = lin & 63;
      As[k][tt] = Xb[(size_t)(i0 + k) * TT + t0 + tt];
      Bs[k][tt] = Wb[(size_t)(i0 + k) * G4 + j0 + tt];
    }
    __syncthreads();
#pragma unroll
    for (int k = 0; k < 16; ++k) {
      float4 av = *(const float4*)&As[k][ty * 4];
      float4 bv = *(const float4*)&Bs[k][tx * 4];
      float a[4] = {av.x, av.y, av.z, av.w};
      float c[4] = {bv.x, bv.y, bv.z, bv.w};
#pragma unroll
      for (int r = 0; r < 4; ++r)
#pragma unroll
        for (int cc = 0; cc < 4; ++cc)
          acc[r][cc] = fmaf(a[r], c[cc], acc[r][cc]);
    }
    __syncthreads();
  }
  const float* bias = bh + (size_t)b * G4;
#pragma unroll
  for (int cc = 0; cc < 4; ++cc) {
    float bv = bias[j0 + tx * 4 + cc];
    __half2 p0 = __floats2half2_rn(acc[0][cc] + bv, acc[1][cc] + bv);
    __half2 p1 = __floats2half2_rn(acc[2][cc] + bv, acc[3][cc] + bv);
    float2 st;
    st.x = __builtin_bit_cast(float, p0);
    st.y = __builtin_bit_cast(float, p1);
    *(float2*)&tile[tx * 4 + cc][ty * 4] = st;
  }
  __syncthreads();
  int jj = tid >> 2;
  int tg = (tid & 3) * 16;
  __half* dst = WXT + ((size_t)b * G4 + j0 + jj) * TT + t0 + tg;
  *(float4*)dst       = *(const float4*)&tile[jj][tg];
  *(float4*)(dst + 8) = *(const float4*)&tile[jj][tg + 8];
}

// ---------------------------------------------------------------------------
// Kernel 2: recurrence.
//  R6 = R4 exchange primitives (the fastest measured: 980us) + 8x poll
//  de-duplication.
//  R5 verdict: sc0 same-XCD path is dead (stale-L2 + write-allocate fetches;
//  demoted to agent loads which are SLOWER than R4's memory-side RMW).
//  R4 verdict: WORKGROUP fetch_add executes memory-side; 512 polls/WG/step
//  (each of 8 waves redundantly polled all 64 slots) drove 600 MB of RMW
//  writebacks = 612 GB/s sustained MALL pressure -> congestion suspect.
//  - Distributed poll: wave w's lanes 0-7 poll ONLY slots w*8..w*8+7
//    (64 RMWs/step/WG, 8x fewer), echo payloads into SHARED scr_sh[64],
//    second lgkm-only barrier, then all waves read peer h from LDS.
//  - Two raw barriers/step now: B2 (echo ready) and B1 (h ready). Both
//    lgkm-only: slot stores/prefetch RMWs float across them.
//  - Hang-proof scaffold unchanged: 6 fast tries -> agent-scope load loop
//    (guaranteed progress via dual publish), 4 fallback steps -> fast off.
//  - Kept: dual publish (workgroup-store fast + agent-store slow),
//    LDS-broadcast dots, cross-step prefetch, hreg output staging, W pinned.
// ---------------------------------------------------------------------------
#define LOADWO(m)                                                            \
  int4 w##m = wpo[m];                                                        \
  asm volatile("" : "+v"(w##m.x), "+v"(w##m.y), "+v"(w##m.z), "+v"(w##m.w));
#define LOADWP(m)                                                            \
  int4 w##m = wpp[m - 16];                                                   \
  asm volatile("" : "+v"(w##m.x), "+v"(w##m.y), "+v"(w##m.z), "+v"(w##m.w));

// own-half dots: uniform LDS broadcast of own h pairs
#define DOTO(m)                                                              \
  {                                                                          \
    int4 hx = hpo[m];                                                        \
    a0 = fdot2i(w##m.x, hx.x, a0);                                           \
    a1 = fdot2i(w##m.y, hx.y, a1);                                           \
    a2 = fdot2i(w##m.z, hx.z, a2);                                           \
    a3 = fdot2i(w##m.w, hx.w, a3);                                           \
  }
// peer-half dots: uniform LDS broadcast from the shared echo
#define DOTP(m)                                                              \
  {                                                                          \
    int4 hx = hpp[m - 16];                                                   \
    a0 = fdot2i(w##m.x, hx.x, a0);                                           \
    a1 = fdot2i(w##m.y, hx.y, a1);                                           \
    a2 = fdot2i(w##m.z, hx.z, a2);                                           \
    a3 = fdot2i(w##m.w, hx.w, a3);                                           \
  }

#define FTAG(vv) ((unsigned)(((vv) >> 32) & 0xFFFull))

__global__ __attribute__((amdgpu_waves_per_eu(2, 2)))
__launch_bounds__(512) void lstm_rec11(const __half* __restrict__ Wc,
                                       const __half* __restrict__ WXT,
                                       const float* __restrict__ h0,
                                       const float* __restrict__ c0,
                                       float* __restrict__ out,
                                       unsigned long long* __restrict__ fsl,
                                       unsigned long long* __restrict__ ssl) {
  __shared__ __align__(16) unsigned int hshd[2][64];  // own-half h pairs, dbuf
  __shared__ __align__(16) unsigned int scr_sh[64];   // SHARED peer echo
  int g    = blockIdx.x;
  int b    = g & 63;
  int half = g >> 6;
  int tid  = threadIdx.x;
  int w    = tid >> 6;
  int lane = tid & 63;
  int i16  = lane & 15;
  int elem = half * 128 + w * 16 + i16;                       // h element
  int j    = (lane >> 4) * 256 + half * 128 + w * 16 + i16;   // gate column
  int kb16 = half * 16;
  bool mine = (lane < 8);          // this wave's polling lanes
  int  s    = w * 8 + (lane & 7);  // slot owned by (wave w, lane)

  // W column, K-halves permuted so blocks 0..15 = own half.
  const int4* wp  = (const int4*)(Wc + ((size_t)b * G4 + j) * HH);
  const int4* wpo = wp + kb16;
  const int4* wpp = wp + (16 - kb16);
  LOADWO(0)  LOADWO(1)  LOADWO(2)  LOADWO(3)  LOADWO(4)  LOADWO(5)  LOADWO(6)  LOADWO(7)
  LOADWO(8)  LOADWO(9)  LOADWO(10) LOADWO(11) LOADWO(12) LOADWO(13) LOADWO(14) LOADWO(15)
  LOADWP(16) LOADWP(17) LOADWP(18) LOADWP(19) LOADWP(20) LOADWP(21) LOADWP(22) LOADWP(23)
  LOADWP(24) LOADWP(25) LOADWP(26) LOADWP(27) LOADWP(28) LOADWP(29) LOADWP(30) LOADWP(31)

  float c_reg = c0[b * HH + elem];

  unsigned long long* fmy = fsl + (size_t)(b * 2 + half) * 2 * 64;
  unsigned long long* fpe = fsl + (size_t)(b * 2 + (half ^ 1)) * 2 * 64;
  unsigned long long* smy = ssl + (size_t)(b * 2 + half) * 2 * 64;
  unsigned long long* spe = ssl + (size_t)(b * 2 + (half ^ 1)) * 2 * 64;

  // Prologue: own-half h0 into LDS + both slot arrays (tag 0, buffer 0).
  if (tid < 64) {
    float f0 = h0[b * HH + half * 128 + 2 * tid];
    float f1 = h0[b * HH + half * 128 + 2 * tid + 1];
    __half2 hp = __floats2half2_rn(f0, f1);
    unsigned int pk = __builtin_bit_cast(unsigned int, hp);
    hshd[0][tid] = pk;
    unsigned long long sv = (unsigned long long)pk;
    __hip_atomic_store(&fmy[tid], sv, __ATOMIC_RELAXED, __HIP_MEMORY_SCOPE_WORKGROUP);
    __hip_atomic_store(&smy[tid], sv, __ATOMIC_RELAXED, __HIP_MEMORY_SCOPE_AGENT);
  }
  __syncthreads();

  const __half* wxTb   = WXT + ((size_t)b * G4 + j) * TT;
  float*        outrow = out + (size_t)b * HH * TT + (size_t)elem * TT;

  int fastp = 1;   // memory-side RMW probe; demoted on repeated fallback
  int fs    = 0;

  // First peer-slot prefetch (t=0, buffer 0): polling lanes only.
  unsigned long long v = 0;
  if (mine)
    v = __hip_atomic_fetch_add(&fpe[s], 1ull << 44,
                               __ATOMIC_RELAXED, __HIP_MEMORY_SCOPE_WORKGROUP);

  float4 wxcur = *(const float4*)(wxTb);   // steps 0..7
  float  hreg[8];
  for (int t8 = 0; t8 < 64; ++t8) {
    float4 wxnext = *(const float4*)(wxTb + ((size_t)((t8 + 1) & 63) * 8));
#pragma unroll
    for (int u = 0; u < 8; ++u) {
      int t = t8 * 8 + u;

      // Own half: 16 wave-uniform b128 broadcast reads (conflict-free).
      const int4* hpo = (const int4*)&hshd[t & 1][0];
      float a0 = 0.f, a1 = 0.f, a2 = 0.f, a3 = 0.f;
      DOTO(0)  DOTO(1)  DOTO(2)  DOTO(3)  DOTO(4)  DOTO(5)  DOTO(6)  DOTO(7)
      DOTO(8)  DOTO(9)  DOTO(10) DOTO(11) DOTO(12) DOTO(13) DOTO(14) DOTO(15)

      float fw = (u < 2) ? wxcur.x : (u < 4) ? wxcur.y : (u < 6) ? wxcur.z : wxcur.w;
      half2_t hp2 = __builtin_bit_cast(half2_t, fw);
      float wx = (float)((u & 1) ? hp2.y : hp2.x);

      // Poll (lanes 0-7 only): bounded fast RMWs, then guaranteed slow loop.
      bool bad = mine && (FTAG(v) != (unsigned)t);
      unsigned long long* psf = fpe + ((size_t)(t & 1) * 64 + s);
      unsigned long long* pss = spe + ((size_t)(t & 1) * 64 + s);
      int tries = 0;
      bool took_slow = false;
      while (__any(bad)) {
        if (bad) {
          if (fastp && tries < 6) {
            v = __hip_atomic_fetch_add(psf, 1ull << 44,
                                       __ATOMIC_RELAXED, __HIP_MEMORY_SCOPE_WORKGROUP);
            ++tries;
          } else {
            v = __hip_atomic_load(pss, __ATOMIC_RELAXED, __HIP_MEMORY_SCOPE_AGENT);
            took_slow = true;
          }
        }
        bad = mine && (FTAG(v) != (unsigned)t);
      }
      if (__any(took_slow)) { if (++fs >= 4) fastp = 0; }

      // Echo into the SHARED scratch; B2 makes it visible to all waves.
      if (mine) scr_sh[s] = (unsigned)v;
      asm volatile("s_waitcnt lgkmcnt(0)" ::: "memory");
      __builtin_amdgcn_s_barrier();

      const int4* hpp = (const int4*)&scr_sh[0];
      DOTP(16) DOTP(17) DOTP(18) DOTP(19) DOTP(20) DOTP(21) DOTP(22) DOTP(23)
      DOTP(24) DOTP(25) DOTP(26) DOTP(27) DOTP(28) DOTP(29) DOTP(30) DOTP(31)

      float gate = fast_tanh((a0 + a1) + (a2 + a3) + wx);

      // Intra-wave i/f/g/o gather (all lanes active: shfl needs live sources).
      float ig = __shfl(gate, i16,      64);
      float fg = __shfl(gate, i16 + 16, 64);
      float gg = __shfl(gate, i16 + 32, 64);
      float og = __shfl(gate, i16 + 48, 64);
      c_reg = c_reg * fast_sig(fg) + fast_sig(ig) * fast_tanh(gg);
      float hval = fast_sig(og) * fast_tanh(c_reg);
      hreg[u] = hval;

      __half hh = __float2half(hval);
      unsigned int hb = (unsigned int)__builtin_bit_cast(unsigned short, hh);
      unsigned int nb = (unsigned int)__shfl_xor((int)hb, 1, 64);
      if (lane < 16) {
        ((__half*)&hshd[(t + 1) & 1][0])[w * 16 + i16] = hh;
        if (!(i16 & 1)) {
          unsigned long long sv =
              ((unsigned long long)(unsigned)(t + 1) << 32) |
              (unsigned long long)(hb | (nb << 16));
          size_t so = (size_t)((t + 1) & 1) * 64 + w * 8 + (i16 >> 1);
          __hip_atomic_store(fmy + so, sv, __ATOMIC_RELAXED, __HIP_MEMORY_SCOPE_WORKGROUP);
          __hip_atomic_store(smy + so, sv, __ATOMIC_RELAXED, __HIP_MEMORY_SCOPE_AGENT);
        }
      }
      // Prefetch peer slots for t+1 (polling lanes; in flight across B1).
      {
        size_t no = (size_t)((t + 1) & 1) * 64 + s;
        if (mine) {
          if (fastp)
            v = __hip_atomic_fetch_add(fpe + no, 1ull << 44,
                                       __ATOMIC_RELAXED, __HIP_MEMORY_SCOPE_WORKGROUP);
          else
            v = __hip_atomic_load(spe + no, __ATOMIC_RELAXED, __HIP_MEMORY_SCOPE_AGENT);
        }
      }
      // B1: h ready for next step. lgkm-only; VMEM stays in flight.
      asm volatile("s_waitcnt lgkmcnt(0)" ::: "memory");
      __builtin_amdgcn_s_barrier();
    }
    if (lane < 16) {   // flush 8 steps of h: 32 B contiguous per output row
      float4 lo = make_float4(hreg[0], hreg[1], hreg[2], hreg[3]);
      float4 hi = make_float4(hreg[4], hreg[5], hreg[6], hreg[7]);
      *(float4*)(outrow + t8 * 8)     = lo;
      *(float4*)(outrow + t8 * 8 + 4) = hi;
    }
    wxcur = wxnext;
  }
  if (lane < 16) out[(size_t)BB * HH * TT + (size_t)b * HH + elem] = c_reg;
}

// ---------------------------------------------------------------------------
extern "C" void kernel_launch(void* const* d_in, const int* in_sizes, int n_in,
                              void* d_out, int out_size, void* d_ws, size_t ws_size,
                              hipStream_t stream) {
  const float* x    = (const float*)d_in[0];
  const float* h0   = (const float*)d_in[1];
  const float* c0   = (const float*)d_in[2];
  const float* W_ih = (const float*)d_in[3];
  const float* W_hh = (const float*)d_in[4];
  const float* b_h  = (const float*)d_in[5];
  float* out = (float*)d_out;

  // Workspace layout:
  //   [0,   32 MB)       Wc   : f16 W_hh transposed, (B,4H,H)
  //   [32,  96 MB)       WXT  : f16 wx+bias, (B,4H,T)  -- t contiguous
  //   [96 MB, +128K)     fsl  : fast slots (workgroup-store / RMW-probe path)
  //   [96 MB+128K,+128K) ssl  : slow slots (agent / MALL path)
  char* ws = (char*)d_ws;
  __half* Wc  = (__half*)ws;
  __half* WXT = (__half*)(ws + (size_t)32 * 1024 * 1024);
  unsigned long long* fsl =
      (unsigned long long*)(ws + (size_t)96 * 1024 * 1024);
  unsigned long long* ssl = fsl + 16384;

  // Tags must never alias a live step value across bench replays: 0xFF.. != any t.
  hipMemsetAsync(fsl, 0xFF, 32768 * sizeof(unsigned long long), stream);
  transpose_whh<<<dim3(G4 / 32, HH / 32, BB), dim3(32, 8), 0, stream>>>(W_hh, Wc);
  gemm_wx<<<dim3(G4 / 64, TT / 64, BB), dim3(256), 0, stream>>>(x, W_ih, b_h, WXT);
  lstm_rec11<<<dim3(128), dim3(512), 0, stream>>>(Wc, WXT, h0, c0, out, fsl, ssl);
}

// Round 7
// 1157.026 us; speedup vs baseline: 1.2626x; 1.0575x over previous
//
#include <hip/hip_runtime.h>
#include <hip/hip_fp16.h>

// Problem constants
#define BB  64
#define CIN 256
#define HH  256
#define TT  512
#define G4  1024   // 4*H

typedef _Float16 half2_t __attribute__((ext_vector_type(2)));

__device__ __forceinline__ float fdot2i(int wi, int hi, float acc) {
  half2_t a = __builtin_bit_cast(half2_t, wi);
  half2_t b = __builtin_bit_cast(half2_t, hi);
  return __builtin_amdgcn_fdot2(a, b, acc, false);
}

__device__ __forceinline__ unsigned int pack2(float a, float b) {
  return __builtin_bit_cast(unsigned int, __floats2half2_rn(a, b));
}

__device__ __forceinline__ float fast_rcp(float x) { return __builtin_amdgcn_rcpf(x); }
__device__ __forceinline__ float fast_sig(float x) {
  return fast_rcp(1.0f + exp2f(-1.4426950408889634f * x));
}
__device__ __forceinline__ float fast_tanh(float x) {
  return 1.0f - 2.0f * fast_rcp(1.0f + exp2f(2.8853900817779268f * x));
}

// ---------------------------------------------------------------------------
// Kernel 0: W_hh (B,H,4H) fp32 -> Wc (B,4H,H) f16  (per-gate-col contiguous)
// ---------------------------------------------------------------------------
__global__ __launch_bounds__(256) void transpose_whh(const float* __restrict__ W,
                                                     __half* __restrict__ Wc) {
  __shared__ __half tile[32][33];
  int b  = blockIdx.z;
  int j0 = blockIdx.x * 32;
  int k0 = blockIdx.y * 32;
  int tx = threadIdx.x;
  int ty = threadIdx.y;
  const float* Wb = W + (size_t)b * HH * G4;
#pragma unroll
  for (int r = 0; r < 32; r += 8)
    tile[ty + r][tx] = __float2half(Wb[(size_t)(k0 + ty + r) * G4 + j0 + tx]);
  __syncthreads();
  __half* out = Wc + (size_t)b * G4 * HH;
#pragma unroll
  for (int r = 0; r < 32; r += 8)
    out[(size_t)(j0 + ty + r) * HH + k0 + tx] = tile[tx][ty + r];
}

// ---------------------------------------------------------------------------
// Kernel 1: WXT[b][j][t] = sum_i x[b][i][t] * W_ih[b][i][j] + b_h[b][j], f16.
//  R7: inner product converted f32 fmaf -> f16 v_dot2_f32_f16 (same primitive
//  as the recurrence; 314 TF ceiling vs 157). Stage k-PAIRS packed as half2:
//  Xp/Wp[16][64] uint (4KB each, was 8KB f32) -- 2x fewer LDS bytes, 2x fewer
//  LDS reads, 2x fewer VALU ops, K-stage 16->32 halves barrier count.
//  Bank audit: Xp quad-read = 4 distinct 16B addrs (conflict-free); Wp = 16
//  addrs over 256B = 2-way (free, m136). Epilogue/bias/transpose unchanged.
//  Numerics: wx inputs now rounded to f16 pre-dot (+~6e-4 pre-tanh, same
//  order as the existing f16 W_hh path).
// ---------------------------------------------------------------------------
__global__ __launch_bounds__(256) void gemm_wx(const float* __restrict__ X,
                                               const float* __restrict__ Wih,
                                               const float* __restrict__ bh,
                                               __half* __restrict__ WXT) {
  __shared__ unsigned int Xp[16][64];   // k-pair x t, packed half2
  __shared__ unsigned int Wp[16][64];   // k-pair x j, packed half2
  __shared__ __half tile[64][72];
  int b  = blockIdx.z;
  int t0 = blockIdx.y * 64;
  int j0 = blockIdx.x * 64;
  int tid = threadIdx.x;
  int tx = tid & 15;
  int ty = tid >> 4;
  const float* Xb = X   + (size_t)b * CIN * TT;
  const float* Wb = Wih + (size_t)b * CIN * G4;
  float acc[4][4] = {};
  for (int i0 = 0; i0 < CIN; i0 += 32) {
#pragma unroll
    for (int q = 0; q < 4; ++q) {
      int lin  = tid + q * 256;    // 0..1023
      int kp   = lin >> 6;         // 0..15 (k-pair row)
      int tt   = lin & 63;
      int krow = i0 + 2 * kp;
      float x0 = Xb[(size_t)krow * TT + t0 + tt];
      float x1 = Xb[(size_t)(krow + 1) * TT + t0 + tt];
      Xp[kp][tt] = pack2(x0, x1);
      float w0 = Wb[(size_t)krow * G4 + j0 + tt];
      float w1 = Wb[(size_t)(krow + 1) * G4 + j0 + tt];
      Wp[kp][tt] = pack2(w0, w1);
    }
    __syncthreads();
#pragma unroll
    for (int kp = 0; kp < 16; ++kp) {
      uint4 xq = *(const uint4*)&Xp[kp][ty * 4];
      uint4 wq = *(const uint4*)&Wp[kp][tx * 4];
      int xr[4] = {(int)xq.x, (int)xq.y, (int)xq.z, (int)xq.w};
      int wc[4] = {(int)wq.x, (int)wq.y, (int)wq.z, (int)wq.w};
#pragma unroll
      for (int r = 0; r < 4; ++r)
#pragma unroll
        for (int c = 0; c < 4; ++c)
          acc[r][c] = fdot2i(xr[r], wc[c], acc[r][c]);
    }
    __syncthreads();
  }
  const float* bias = bh + (size_t)b * G4;
#pragma unroll
  for (int cc = 0; cc < 4; ++cc) {
    float bv = bias[j0 + tx * 4 + cc];
    __half2 p0 = __floats2half2_rn(acc[0][cc] + bv, acc[1][cc] + bv);
    __half2 p1 = __floats2half2_rn(acc[2][cc] + bv, acc[3][cc] + bv);
    float2 st;
    st.x = __builtin_bit_cast(float, p0);
    st.y = __builtin_bit_cast(float, p1);
    *(float2*)&tile[tx * 4 + cc][ty * 4] = st;
  }
  __syncthreads();
  int jj = tid >> 2;
  int tg = (tid & 3) * 16;
  __half* dst = WXT + ((size_t)b * G4 + j0 + jj) * TT + t0 + tg;
  *(float4*)dst       = *(const float4*)&tile[jj][tg];
  *(float4*)(dst + 8) = *(const float4*)&tile[jj][tg + 8];
}

// ---------------------------------------------------------------------------
// Kernel 2: recurrence. BYTE-IDENTICAL to R6 (the 780us/25.5% control):
//  distributed poll (wave w lanes 0-7 -> slots w*8..w*8+7, 64 memory-side
//  RMWs/step/WG), shared LDS echo + 2 lgkm-only barriers/step, dual publish
//  (workgroup-store fast + agent-store slow), hang-proof bounded fallback,
//  LDS-broadcast dots, cross-step prefetch, hreg output staging, W pinned.
// ---------------------------------------------------------------------------
#define LOADWO(m)                                                            \
  int4 w##m = wpo[m];                                                        \
  asm volatile("" : "+v"(w##m.x), "+v"(w##m.y), "+v"(w##m.z), "+v"(w##m.w));
#define LOADWP(m)                                                            \
  int4 w##m = wpp[m - 16];                                                   \
  asm volatile("" : "+v"(w##m.x), "+v"(w##m.y), "+v"(w##m.z), "+v"(w##m.w));

// own-half dots: uniform LDS broadcast of own h pairs
#define DOTO(m)                                                              \
  {                                                                          \
    int4 hx = hpo[m];                                                        \
    a0 = fdot2i(w##m.x, hx.x, a0);                                           \
    a1 = fdot2i(w##m.y, hx.y, a1);                                           \
    a2 = fdot2i(w##m.z, hx.z, a2);                                           \
    a3 = fdot2i(w##m.w, hx.w, a3);                                           \
  }
// peer-half dots: uniform LDS broadcast from the shared echo
#define DOTP(m)                                                              \
  {                                                                          \
    int4 hx = hpp[m - 16];                                                   \
    a0 = fdot2i(w##m.x, hx.x, a0);                                           \
    a1 = fdot2i(w##m.y, hx.y, a1);                                           \
    a2 = fdot2i(w##m.z, hx.z, a2);                                           \
    a3 = fdot2i(w##m.w, hx.w, a3);                                           \
  }

#define FTAG(vv) ((unsigned)(((vv) >> 32) & 0xFFFull))

__global__ __attribute__((amdgpu_waves_per_eu(2, 2)))
__launch_bounds__(512) void lstm_rec11(const __half* __restrict__ Wc,
                                       const __half* __restrict__ WXT,
                                       const float* __restrict__ h0,
                                       const float* __restrict__ c0,
                                       float* __restrict__ out,
                                       unsigned long long* __restrict__ fsl,
                                       unsigned long long* __restrict__ ssl) {
  __shared__ __align__(16) unsigned int hshd[2][64];  // own-half h pairs, dbuf
  __shared__ __align__(16) unsigned int scr_sh[64];   // SHARED peer echo
  int g    = blockIdx.x;
  int b    = g & 63;
  int half = g >> 6;
  int tid  = threadIdx.x;
  int w    = tid >> 6;
  int lane = tid & 63;
  int i16  = lane & 15;
  int elem = half * 128 + w * 16 + i16;                       // h element
  int j    = (lane >> 4) * 256 + half * 128 + w * 16 + i16;   // gate column
  int kb16 = half * 16;
  bool mine = (lane < 8);          // this wave's polling lanes
  int  s    = w * 8 + (lane & 7);  // slot owned by (wave w, lane)

  // W column, K-halves permuted so blocks 0..15 = own half.
  const int4* wp  = (const int4*)(Wc + ((size_t)b * G4 + j) * HH);
  const int4* wpo = wp + kb16;
  const int4* wpp = wp + (16 - kb16);
  LOADWO(0)  LOADWO(1)  LOADWO(2)  LOADWO(3)  LOADWO(4)  LOADWO(5)  LOADWO(6)  LOADWO(7)
  LOADWO(8)  LOADWO(9)  LOADWO(10) LOADWO(11) LOADWO(12) LOADWO(13) LOADWO(14) LOADWO(15)
  LOADWP(16) LOADWP(17) LOADWP(18) LOADWP(19) LOADWP(20) LOADWP(21) LOADWP(22) LOADWP(23)
  LOADWP(24) LOADWP(25) LOADWP(26) LOADWP(27) LOADWP(28) LOADWP(29) LOADWP(30) LOADWP(31)

  float c_reg = c0[b * HH + elem];

  unsigned long long* fmy = fsl + (size_t)(b * 2 + half) * 2 * 64;
  unsigned long long* fpe = fsl + (size_t)(b * 2 + (half ^ 1)) * 2 * 64;
  unsigned long long* smy = ssl + (size_t)(b * 2 + half) * 2 * 64;
  unsigned long long* spe = ssl + (size_t)(b * 2 + (half ^ 1)) * 2 * 64;

  // Prologue: own-half h0 into LDS + both slot arrays (tag 0, buffer 0).
  if (tid < 64) {
    float f0 = h0[b * HH + half * 128 + 2 * tid];
    float f1 = h0[b * HH + half * 128 + 2 * tid + 1];
    __half2 hp = __floats2half2_rn(f0, f1);
    unsigned int pk = __builtin_bit_cast(unsigned int, hp);
    hshd[0][tid] = pk;
    unsigned long long sv = (unsigned long long)pk;
    __hip_atomic_store(&fmy[tid], sv, __ATOMIC_RELAXED, __HIP_MEMORY_SCOPE_WORKGROUP);
    __hip_atomic_store(&smy[tid], sv, __ATOMIC_RELAXED, __HIP_MEMORY_SCOPE_AGENT);
  }
  __syncthreads();

  const __half* wxTb   = WXT + ((size_t)b * G4 + j) * TT;
  float*        outrow = out + (size_t)b * HH * TT + (size_t)elem * TT;

  int fastp = 1;   // memory-side RMW probe; demoted on repeated fallback
  int fs    = 0;

  // First peer-slot prefetch (t=0, buffer 0): polling lanes only.
  unsigned long long v = 0;
  if (mine)
    v = __hip_atomic_fetch_add(&fpe[s], 1ull << 44,
                               __ATOMIC_RELAXED, __HIP_MEMORY_SCOPE_WORKGROUP);

  float4 wxcur = *(const float4*)(wxTb);   // steps 0..7
  float  hreg[8];
  for (int t8 = 0; t8 < 64; ++t8) {
    float4 wxnext = *(const float4*)(wxTb + ((size_t)((t8 + 1) & 63) * 8));
#pragma unroll
    for (int u = 0; u < 8; ++u) {
      int t = t8 * 8 + u;

      // Own half: 16 wave-uniform b128 broadcast reads (conflict-free).
      const int4* hpo = (const int4*)&hshd[t & 1][0];
      float a0 = 0.f, a1 = 0.f, a2 = 0.f, a3 = 0.f;
      DOTO(0)  DOTO(1)  DOTO(2)  DOTO(3)  DOTO(4)  DOTO(5)  DOTO(6)  DOTO(7)
      DOTO(8)  DOTO(9)  DOTO(10) DOTO(11) DOTO(12) DOTO(13) DOTO(14) DOTO(15)

      float fw = (u < 2) ? wxcur.x : (u < 4) ? wxcur.y : (u < 6) ? wxcur.z : wxcur.w;
      half2_t hp2 = __builtin_bit_cast(half2_t, fw);
      float wx = (float)((u & 1) ? hp2.y : hp2.x);

      // Poll (lanes 0-7 only): bounded fast RMWs, then guaranteed slow loop.
      bool bad = mine && (FTAG(v) != (unsigned)t);
      unsigned long long* psf = fpe + ((size_t)(t & 1) * 64 + s);
      unsigned long long* pss = spe + ((size_t)(t & 1) * 64 + s);
      int tries = 0;
      bool took_slow = false;
      while (__any(bad)) {
        if (bad) {
          if (fastp && tries < 6) {
            v = __hip_atomic_fetch_add(psf, 1ull << 44,
                                       __ATOMIC_RELAXED, __HIP_MEMORY_SCOPE_WORKGROUP);
            ++tries;
          } else {
            v = __hip_atomic_load(pss, __ATOMIC_RELAXED, __HIP_MEMORY_SCOPE_AGENT);
            took_slow = true;
          }
        }
        bad = mine && (FTAG(v) != (unsigned)t);
      }
      if (__any(took_slow)) { if (++fs >= 4) fastp = 0; }

      // Echo into the SHARED scratch; B2 makes it visible to all waves.
      if (mine) scr_sh[s] = (unsigned)v;
      asm volatile("s_waitcnt lgkmcnt(0)" ::: "memory");
      __builtin_amdgcn_s_barrier();

      const int4* hpp = (const int4*)&scr_sh[0];
      DOTP(16) DOTP(17) DOTP(18) DOTP(19) DOTP(20) DOTP(21) DOTP(22) DOTP(23)
      DOTP(24) DOTP(25) DOTP(26) DOTP(27) DOTP(28) DOTP(29) DOTP(30) DOTP(31)

      float gate = fast_tanh((a0 + a1) + (a2 + a3) + wx);

      // Intra-wave i/f/g/o gather (all lanes active: shfl needs live sources).
      float ig = __shfl(gate, i16,      64);
      float fg = __shfl(gate, i16 + 16, 64);
      float gg = __shfl(gate, i16 + 32, 64);
      float og = __shfl(gate, i16 + 48, 64);
      c_reg = c_reg * fast_sig(fg) + fast_sig(ig) * fast_tanh(gg);
      float hval = fast_sig(og) * fast_tanh(c_reg);
      hreg[u] = hval;

      __half hh = __float2half(hval);
      unsigned int hb = (unsigned int)__builtin_bit_cast(unsigned short, hh);
      unsigned int nb = (unsigned int)__shfl_xor((int)hb, 1, 64);
      if (lane < 16) {
        ((__half*)&hshd[(t + 1) & 1][0])[w * 16 + i16] = hh;
        if (!(i16 & 1)) {
          unsigned long long sv =
              ((unsigned long long)(unsigned)(t + 1) << 32) |
              (unsigned long long)(hb | (nb << 16));
          size_t so = (size_t)((t + 1) & 1) * 64 + w * 8 + (i16 >> 1);
          __hip_atomic_store(fmy + so, sv, __ATOMIC_RELAXED, __HIP_MEMORY_SCOPE_WORKGROUP);
          __hip_atomic_store(smy + so, sv, __ATOMIC_RELAXED, __HIP_MEMORY_SCOPE_AGENT);
        }
      }
      // Prefetch peer slots for t+1 (polling lanes; in flight across B1).
      {
        size_t no = (size_t)((t + 1) & 1) * 64 + s;
        if (mine) {
          if (fastp)
            v = __hip_atomic_fetch_add(fpe + no, 1ull << 44,
                                       __ATOMIC_RELAXED, __HIP_MEMORY_SCOPE_WORKGROUP);
          else
            v = __hip_atomic_load(spe + no, __ATOMIC_RELAXED, __HIP_MEMORY_SCOPE_AGENT);
        }
      }
      // B1: h ready for next step. lgkm-only; VMEM stays in flight.
      asm volatile("s_waitcnt lgkmcnt(0)" ::: "memory");
      __builtin_amdgcn_s_barrier();
    }
    if (lane < 16) {   // flush 8 steps of h: 32 B contiguous per output row
      float4 lo = make_float4(hreg[0], hreg[1], hreg[2], hreg[3]);
      float4 hi = make_float4(hreg[4], hreg[5], hreg[6], hreg[7]);
      *(float4*)(outrow + t8 * 8)     = lo;
      *(float4*)(outrow + t8 * 8 + 4) = hi;
    }
    wxcur = wxnext;
  }
  if (lane < 16) out[(size_t)BB * HH * TT + (size_t)b * HH + elem] = c_reg;
}

// ---------------------------------------------------------------------------
extern "C" void kernel_launch(void* const* d_in, const int* in_sizes, int n_in,
                              void* d_out, int out_size, void* d_ws, size_t ws_size,
                              hipStream_t stream) {
  const float* x    = (const float*)d_in[0];
  const float* h0   = (const float*)d_in[1];
  const float* c0   = (const float*)d_in[2];
  const float* W_ih = (const float*)d_in[3];
  const float* W_hh = (const float*)d_in[4];
  const float* b_h  = (const float*)d_in[5];
  float* out = (float*)d_out;

  // Workspace layout:
  //   [0,   32 MB)       Wc   : f16 W_hh transposed, (B,4H,H)
  //   [32,  96 MB)       WXT  : f16 wx+bias, (B,4H,T)  -- t contiguous
  //   [96 MB, +128K)     fsl  : fast slots (workgroup-store / RMW-probe path)
  //   [96 MB+128K,+128K) ssl  : slow slots (agent / MALL path)
  char* ws = (char*)d_ws;
  __half* Wc  = (__half*)ws;
  __half* WXT = (__half*)(ws + (size_t)32 * 1024 * 1024);
  unsigned long long* fsl =
      (unsigned long long*)(ws + (size_t)96 * 1024 * 1024);
  unsigned long long* ssl = fsl + 16384;

  // Tags must never alias a live step value across bench replays: 0xFF.. != any t.
  hipMemsetAsync(fsl, 0xFF, 32768 * sizeof(unsigned long long), stream);
  transpose_whh<<<dim3(G4 / 32, HH / 32, BB), dim3(32, 8), 0, stream>>>(W_hh, Wc);
  gemm_wx<<<dim3(G4 / 64, TT / 64, BB), dim3(256), 0, stream>>>(x, W_ih, b_h, WXT);
  lstm_rec11<<<dim3(128), dim3(512), 0, stream>>>(Wc, WXT, h0, c0, out, fsl, ssl);
}